// Round 1
// baseline (202.072 us; speedup 1.0000x reference)
//
#include <hip/hip_runtime.h>

#define NB 64
#define NT 2048
#define NQD 512
#define NKD 512
#define NVD 512
#define NAD 256

typedef __attribute__((ext_vector_type(8))) short s16x8;
typedef __attribute__((ext_vector_type(4))) float fx4;

__device__ __forceinline__ short f2bf(float x) {
  union { float f; unsigned u; } v; v.f = x;
  return (short)((v.u + 0x7fffu + ((v.u >> 16) & 1u)) >> 16);  // RNE
}

// ---- kernel 1: qpk[b][n] = query[b,:]·Wq[:,n] + bq[n] + bk[n]
__global__ void qpk_kernel(const float* __restrict__ query, const float* __restrict__ Wq,
                           const float* __restrict__ bq, const float* __restrict__ bk,
                           float* __restrict__ qpk) {
  __shared__ float q[NQD];
  const int b = blockIdx.x, n = threadIdx.x;
  for (int k = n; k < NQD; k += 256) q[k] = query[b * NQD + k];
  __syncthreads();
  float acc = bq[n] + bk[n];
#pragma unroll 8
  for (int k = 0; k < NQD; ++k) acc += q[k] * Wq[k * NAD + n];
  qpk[b * NAD + n] = acc;
}

// ---- kernel 2: WkT[a][k] = bf16(Wk[k][a])   (transpose + convert, LDS-tiled)
__global__ void wkt_kernel(const float* __restrict__ Wk, short* __restrict__ WkT) {
  __shared__ float tile[64][65];
  const int kb = (blockIdx.x & 7) * 64;   // 512/64 = 8 k-tiles
  const int ab = (blockIdx.x >> 3) * 64;  // 256/64 = 4 a-tiles
  const int tid = threadIdx.x;
  const int c = tid & 63, r0 = tid >> 6;
#pragma unroll
  for (int rr = r0; rr < 64; rr += 4)
    tile[rr][c] = Wk[(size_t)(kb + rr) * NAD + ab + c];
  __syncthreads();
#pragma unroll
  for (int rr = r0; rr < 64; rr += 4)
    WkT[(size_t)(ab + rr) * NKD + kb + c] = f2bf(tile[c][rr]);
}

// ---- kernel 3: fused GEMM(key@Wk) + tanh + ·Wo reduce -> score[b*T + t]
// 4 waves, BM=64 rows, BN=256 (full AD, 64 n per wave), BK=32.
__global__ void __launch_bounds__(256)
score_kernel(const float* __restrict__ key, const short* __restrict__ WkT,
             const float* __restrict__ qpk, const float* __restrict__ Wo,
             float* __restrict__ score) {
  __shared__ short As[64 * 32];
  __shared__ short Bs[256 * 32];
  __shared__ float sred[4][64];
  const int tid = threadIdx.x;
  const int w = tid >> 6;          // wave 0..3 -> n range [w*64, w*64+64)
  const int l = tid & 63;
  const int g = l >> 4;            // k-group
  const int h = l & 15;            // m (A) / n (B) within 16-tile
  const int m0 = blockIdx.x * 64;  // global row (b*T + t), tiles never span batches
  const int b = m0 >> 11;          // /T

  float qv[4], wv[4];
#pragma unroll
  for (int nt = 0; nt < 4; ++nt) {
    const int n = w * 64 + nt * 16 + h;
    qv[nt] = qpk[b * NAD + n];
    wv[nt] = Wo[n];
  }

  fx4 acc[4][4];
#pragma unroll
  for (int i = 0; i < 4; ++i)
#pragma unroll
    for (int j = 0; j < 4; ++j) acc[i][j] = fx4{0.f, 0.f, 0.f, 0.f};

  const int ar = tid >> 2;         // A stage: row 0..63
  const int ac = (tid & 3) * 8;    // A stage: k offset

  for (int k0 = 0; k0 < NKD; k0 += 32) {
    // stage A tile [64 rows][32 k], f32 -> bf16; LDS writes are tid*16B contiguous
    const float* gp = key + (size_t)(m0 + ar) * NKD + k0 + ac;
    fx4 x0 = *(const fx4*)gp;
    fx4 x1 = *(const fx4*)(gp + 4);
    s16x8 av;
    av[0] = f2bf(x0[0]); av[1] = f2bf(x0[1]); av[2] = f2bf(x0[2]); av[3] = f2bf(x0[3]);
    av[4] = f2bf(x1[0]); av[5] = f2bf(x1[1]); av[6] = f2bf(x1[2]); av[7] = f2bf(x1[3]);
    *(s16x8*)(&As[ar * 32 + ac]) = av;
    // stage B tile [256 n][32 k] (already bf16, B^T layout): linear 16B chunks
#pragma unroll
    for (int rep = 0; rep < 4; ++rep) {
      const int ch = tid + rep * 256;
      const int n = ch >> 2, part = ch & 3;
      s16x8 bv = *(const s16x8*)(WkT + (size_t)n * NKD + k0 + part * 8);
      *(s16x8*)(&Bs[ch * 8]) = bv;
    }
    __syncthreads();
    s16x8 af[4], bfr[4];
#pragma unroll
    for (int mt = 0; mt < 4; ++mt)
      af[mt] = *(const s16x8*)(&As[(mt * 16 + h) * 32 + g * 8]);
#pragma unroll
    for (int nt = 0; nt < 4; ++nt)
      bfr[nt] = *(const s16x8*)(&Bs[(w * 64 + nt * 16 + h) * 32 + g * 8]);
#pragma unroll
    for (int mt = 0; mt < 4; ++mt)
#pragma unroll
      for (int nt = 0; nt < 4; ++nt)
        acc[mt][nt] = __builtin_amdgcn_mfma_f32_16x16x32_bf16(af[mt], bfr[nt], acc[mt][nt], 0, 0, 0);
    __syncthreads();
  }

  // epilogue: score partial = sum_n tanh(kp + qpk)·Wo  (C layout: col=h, row=4g+reg)
#pragma unroll
  for (int mt = 0; mt < 4; ++mt) {
#pragma unroll
    for (int r = 0; r < 4; ++r) {
      float s = tanhf(acc[mt][0][r] + qv[0]) * wv[0]
              + tanhf(acc[mt][1][r] + qv[1]) * wv[1]
              + tanhf(acc[mt][2][r] + qv[2]) * wv[2]
              + tanhf(acc[mt][3][r] + qv[3]) * wv[3];
#pragma unroll
      for (int off = 1; off < 16; off <<= 1) s += __shfl_xor(s, off, 64);
      if (h == 0) sred[w][mt * 16 + g * 4 + r] = s;
    }
  }
  __syncthreads();
  if (tid < 64)
    score[m0 + tid] = sred[0][tid] + sred[1][tid] + sred[2][tid] + sred[3][tid];
}

// ---- kernel 4: softmax over T per batch (bo dropped: softmax shift-invariant)
__global__ void softmax_kernel(const float* __restrict__ score, float* __restrict__ attn) {
  __shared__ float redm[4];
  __shared__ float reds[4];
  const int b = blockIdx.x, tid = threadIdx.x;
  const float* s = score + (size_t)b * NT;
  float v[8];
  float m = -3.0e38f;
#pragma unroll
  for (int j = 0; j < 8; ++j) { v[j] = s[tid + j * 256]; m = fmaxf(m, v[j]); }
#pragma unroll
  for (int off = 1; off < 64; off <<= 1) m = fmaxf(m, __shfl_xor(m, off, 64));
  if ((tid & 63) == 0) redm[tid >> 6] = m;
  __syncthreads();
  m = fmaxf(fmaxf(redm[0], redm[1]), fmaxf(redm[2], redm[3]));
  float sum = 0.f;
#pragma unroll
  for (int j = 0; j < 8; ++j) { v[j] = __expf(v[j] - m); sum += v[j]; }
#pragma unroll
  for (int off = 1; off < 64; off <<= 1) sum += __shfl_xor(sum, off, 64);
  if ((tid & 63) == 0) reds[tid >> 6] = sum;
  __syncthreads();
  sum = reds[0] + reds[1] + reds[2] + reds[3];
  const float inv = 1.0f / sum;
#pragma unroll
  for (int j = 0; j < 8; ++j) attn[(size_t)b * NT + tid + j * 256] = v[j] * inv;
}

// ---- kernel 5: partial context over 64-row t-chunks (no atomics, deterministic)
__global__ void ctx_partial_kernel(const float* __restrict__ attn, const float* __restrict__ value,
                                   float* __restrict__ partial) {
  __shared__ float a[64];
  const int blk = blockIdx.x;       // b*32 + tc
  const int b = blk >> 5, tc = blk & 31;
  const int tid = threadIdx.x;
  if (tid < 64) a[tid] = attn[(size_t)b * NT + tc * 64 + tid];
  __syncthreads();
  const float* vp = value + ((size_t)b * NT + tc * 64) * NVD + tid * 2;
  float ax = 0.f, ay = 0.f;
#pragma unroll 4
  for (int t = 0; t < 64; ++t) {
    float2 x = *(const float2*)(vp + (size_t)t * NVD);
    ax += a[t] * x.x;
    ay += a[t] * x.y;
  }
  float* o = partial + (size_t)blk * NVD + tid * 2;
  o[0] = ax;
  o[1] = ay;
}

// ---- kernel 6: reduce partials -> context
__global__ void ctx_reduce_kernel(const float* __restrict__ partial, float* __restrict__ ctx) {
  const int i = blockIdx.x * 256 + threadIdx.x;  // < NB*NVD
  const int b = i >> 9, v = i & (NVD - 1);
  float s = 0.f;
#pragma unroll
  for (int tc = 0; tc < 32; ++tc) s += partial[(size_t)(b * 32 + tc) * NVD + v];
  ctx[i] = s;
}

extern "C" void kernel_launch(void* const* d_in, const int* in_sizes, int n_in,
                              void* d_out, int out_size, void* d_ws, size_t ws_size,
                              hipStream_t stream) {
  const float* query = (const float*)d_in[0];
  const float* key   = (const float*)d_in[1];
  const float* value = (const float*)d_in[2];
  const float* Wq    = (const float*)d_in[3];
  const float* bq    = (const float*)d_in[4];
  const float* Wk    = (const float*)d_in[5];
  const float* bk    = (const float*)d_in[6];
  const float* Wo    = (const float*)d_in[7];
  // d_in[8] = bo: unused — softmax over T is invariant to a uniform shift,
  // and only (context, attn) are returned.

  float* out  = (float*)d_out;
  float* ctx  = out;                // [B][VD]
  float* attn = out + NB * NVD;     // [B][T]

  char* ws = (char*)d_ws;
  float* qpk     = (float*)(ws);                                   // 64 KB
  short* WkT     = (short*)(ws + 64 * 1024);                       // 256 KB
  float* score   = (float*)(ws + (64 + 256) * 1024);               // 512 KB
  float* partial = (float*)(ws + (64 + 256 + 512) * 1024);         // 4 MB

  qpk_kernel<<<NB, 256, 0, stream>>>(query, Wq, bq, bk, qpk);
  wkt_kernel<<<32, 256, 0, stream>>>(Wk, WkT);
  score_kernel<<<(NB * NT) / 64, 256, 0, stream>>>(key, WkT, qpk, Wo, score);
  softmax_kernel<<<NB, 256, 0, stream>>>(score, attn);
  ctx_partial_kernel<<<NB * 32, 256, 0, stream>>>(attn, value, partial);
  ctx_reduce_kernel<<<(NB * NVD) / 256, 256, 0, stream>>>(partial, ctx);
}